// Round 2
// baseline (467.711 us; speedup 1.0000x reference)
//
#include <hip/hip_runtime.h>
#include <cmath>

#define NB 16
#define NL 64
#define NP 512
#define NH 128
#define NG 10
#define ROWS (NB * NL * NP)          // 524288 rows

// output layout (flat float32, reference return order)
#define OFF_PI    ((size_t)0)
#define OFF_SIGMA ((size_t)5242880)
#define OFF_MU    ((size_t)10485760)
#define OFF_DIST  ((size_t)15728640)
#define OFF_MASK  ((size_t)16252928)

// LDS tile: 256 rows x 32 k, padded 32 -> 36 floats per row.
// row*36*4 B = row*144 B : 16B-aligned -> float4 LDS read/write.
// b128 access bank map: lane l touches banks {4l..4l+3 mod 32};
// every 8-lane group covers all 32 banks exactly once -> conflict-free.
#define XPAD 36

// ---------------------------------------------------------------------------
// Fused kernel: min-dist over 24 atoms + 3x GEMV [128 -> 10] + activations.
// One thread per (b, l, p) == one row of Interact. 256 rows per block.
// Register-prefetch double buffering: stage kc+1 global loads are issued
// before computing stage kc; stage 0 loads hide under the dist computation.
// Weights/biases are read with wave-uniform indices -> s_load (scalar pipe).
// ---------------------------------------------------------------------------
__global__ __launch_bounds__(256, 4) void k_fused(
    const float* __restrict__ pos_l,   // [B, NL, 3]
    const float* __restrict__ pos_p,   // [B, NP, 24, 3]
    const int*   __restrict__ mask,    // [B, NL, NP] (bool as int32)
    const float* __restrict__ X,       // [ROWS, 128]
    const float* __restrict__ Wpi, const float* __restrict__ bpi,
    const float* __restrict__ Wsg, const float* __restrict__ bsg,
    const float* __restrict__ Wmu, const float* __restrict__ bmu,
    float* __restrict__ out_pi,
    float* __restrict__ out_sg,
    float* __restrict__ out_mu,
    float* __restrict__ dist_out,
    float* __restrict__ mask_out)
{
    __shared__ __align__(16) float xs[256 * XPAD];   // 36 KB -> 4 blocks/CU

    const int tid = threadIdx.x;
    const int idx = blockIdx.x * 256 + tid;     // b*NL*NP + l*NP + p
    const size_t row0 = (size_t)blockIdx.x * 256;

    // Cooperative-load slot mapping (same for every stage):
    // slot s = j*256+tid, r = s>>3, k4 = s&7 -> wave covers 8 rows x 128B.
    int sr[8], sk[8];
    #pragma unroll
    for (int j = 0; j < 8; ++j) {
        int s = j * 256 + tid;
        sr[j] = s >> 3;
        sk[j] = s & 7;
    }

    // ---- issue stage-0 prefetch (latency hides under dist part) ----
    float4 pf[8];
    #pragma unroll
    for (int j = 0; j < 8; ++j)
        pf[j] = *(const float4*)(X + (row0 + sr[j]) * NH + sk[j] * 4);

    // ---------------- distance part ----------------
    {
        int p  = idx & (NP - 1);
        int bl = idx >> 9;                      // b*NL + l
        int b  = bl >> 6;

        const float* xl = pos_l + bl * 3;
        float x0 = xl[0], x1 = xl[1], x2 = xl[2];
        float qs = x0 * x0 + x1 * x1 + x2 * x2;

        // 24 atoms * 3 floats = 18 float4 per residue (288B rows, 16B aligned)
        const float4* yp = (const float4*)(pos_p + ((size_t)(b * NP + p)) * 72);

        // min over clamped d2; d2<0 -> NaN -> 10000 in the reference:
        // clamp to 1e8 (=10000^2 exactly) and take one sqrt at the end.
        float m2 = 1e30f;
        #pragma unroll
        for (int q = 0; q < 6; ++q) {           // 4 atoms per iteration
            float4 v0 = yp[q * 3 + 0];
            float4 v1 = yp[q * 3 + 1];
            float4 v2 = yp[q * 3 + 2];
            float c[12] = {v0.x, v0.y, v0.z, v0.w,
                           v1.x, v1.y, v1.z, v1.w,
                           v2.x, v2.y, v2.z, v2.w};
            #pragma unroll
            for (int a = 0; a < 4; ++a) {
                float yx = c[a * 3 + 0], yy = c[a * 3 + 1], yz = c[a * 3 + 2];
                float d2 = qs + (yx * yx + yy * yy + yz * yz)
                              - 2.0f * (x0 * yx + x1 * yy + x2 * yz);
                d2 = (d2 >= 0.0f) ? d2 : 1e8f;
                m2 = fminf(m2, d2);
            }
        }
        float m = sqrtf(m2);

        int mk = mask[idx];
        dist_out[idx] = mk ? m : 0.0f;
        mask_out[idx] = mk ? 1.0f : 0.0f;
    }

    // ---------------- GEMV part ----------------
    float accp[NG], accs[NG], accm[NG];
    #pragma unroll
    for (int g = 0; g < NG; ++g) {              // uniform-index -> s_load
        accp[g] = bpi[g];
        accs[g] = bsg[g];
        accm[g] = bmu[g];
    }

    for (int kc = 0; kc < 4; ++kc) {
        __syncthreads();                        // prev-stage reads complete
        #pragma unroll
        for (int j = 0; j < 8; ++j)             // regs -> LDS (b128 writes)
            *(float4*)&xs[sr[j] * XPAD + sk[j] * 4] = pf[j];
        __syncthreads();                        // tile visible to all

        if (kc < 3) {                           // issue next-stage loads;
            #pragma unroll                      // they fly during compute
            for (int j = 0; j < 8; ++j)
                pf[j] = *(const float4*)(X + (row0 + sr[j]) * NH
                                           + (kc + 1) * 32 + sk[j] * 4);
        }

        const float4* xr4 = (const float4*)&xs[tid * XPAD];
        #pragma unroll
        for (int k4 = 0; k4 < 8; ++k4) {
            float4 h4 = xr4[k4];                // ds_read_b128, conflict-free
            float hk[4] = {h4.x, h4.y, h4.z, h4.w};
            #pragma unroll
            for (int kk = 0; kk < 4; ++kk) {
                int kg = kc * 32 + k4 * 4 + kk; // wave-uniform
                const float* wp = Wpi + kg * NG;
                const float* ws = Wsg + kg * NG;
                const float* wm = Wmu + kg * NG;
                float h = hk[kk];
                #pragma unroll
                for (int g = 0; g < NG; ++g) {
                    accp[g] = fmaf(h, wp[g], accp[g]);
                    accs[g] = fmaf(h, ws[g], accs[g]);
                    accm[g] = fmaf(h, wm[g], accm[g]);
                }
            }
        }
    }

    // ---------------- epilogue ----------------
    const size_t ro = (size_t)idx * NG;         // byte offset idx*40: 8-aligned

    // pi = softmax(accp)
    float mx = accp[0];
    #pragma unroll
    for (int g = 1; g < NG; ++g) mx = fmaxf(mx, accp[g]);
    float e[NG], ssum = 0.0f;
    #pragma unroll
    for (int g = 0; g < NG; ++g) { e[g] = __expf(accp[g] - mx); ssum += e[g]; }
    float inv = 1.0f / ssum;
    #pragma unroll
    for (int g = 0; g < 5; ++g)
        *(float2*)&out_pi[ro + 2 * g] = make_float2(e[2 * g] * inv,
                                                    e[2 * g + 1] * inv);

    // sigma = clip(leaky(accs) + 1.1, 1e-6, inf)
    float sg[NG];
    #pragma unroll
    for (int g = 0; g < NG; ++g) {
        float x = accs[g];
        sg[g] = fmaxf((x >= 0.0f ? x : 0.01f * x) + 1.1f, 1e-6f);
    }
    #pragma unroll
    for (int g = 0; g < 5; ++g)
        *(float2*)&out_sg[ro + 2 * g] = make_float2(sg[2 * g], sg[2 * g + 1]);

    // mu = leaky(accm) + 1.0
    float mu[NG];
    #pragma unroll
    for (int g = 0; g < NG; ++g) {
        float x = accm[g];
        mu[g] = (x >= 0.0f ? x : 0.01f * x) + 1.0f;
    }
    #pragma unroll
    for (int g = 0; g < 5; ++g)
        *(float2*)&out_mu[ro + 2 * g] = make_float2(mu[2 * g], mu[2 * g + 1]);
}

// ---------------------------------------------------------------------------
extern "C" void kernel_launch(void* const* d_in, const int* in_sizes, int n_in,
                              void* d_out, int out_size, void* d_ws, size_t ws_size,
                              hipStream_t stream) {
    const float* pos_l    = (const float*)d_in[0];
    const float* pos_p    = (const float*)d_in[1];
    const float* Interact = (const float*)d_in[2];
    const int*   mask     = (const int*)  d_in[3];
    const float* Wpi      = (const float*)d_in[4];
    const float* bpi      = (const float*)d_in[5];
    const float* Wsg      = (const float*)d_in[6];
    const float* bsg      = (const float*)d_in[7];
    const float* Wmu      = (const float*)d_in[8];
    const float* bmu      = (const float*)d_in[9];

    float* out      = (float*)d_out;
    float* out_pi   = out + OFF_PI;
    float* out_sg   = out + OFF_SIGMA;
    float* out_mu   = out + OFF_MU;
    float* out_dist = out + OFF_DIST;
    float* out_mask = out + OFF_MASK;

    hipLaunchKernelGGL(k_fused, dim3(ROWS / 256), dim3(256), 0, stream,
                       pos_l, pos_p, mask, Interact,
                       Wpi, bpi, Wsg, bsg, Wmu, bmu,
                       out_pi, out_sg, out_mu, out_dist, out_mask);
}

// Round 3
// 461.512 us; speedup vs baseline: 1.0134x; 1.0134x over previous
//
#include <hip/hip_runtime.h>
#include <cmath>

#define NB 16
#define NL 64
#define NP 512
#define NH 128
#define NG 10
#define ROWS (NB * NL * NP)          // 524288 rows

// output layout (flat float32, reference return order)
#define OFF_PI    ((size_t)0)
#define OFF_SIGMA ((size_t)5242880)
#define OFF_MU    ((size_t)10485760)
#define OFF_DIST  ((size_t)15728640)
#define OFF_MASK  ((size_t)16252928)

// LDS tile: 256 rows x 32 k, padded 32 -> 36 floats per row.
// row*36*4 B = row*144 B : 16B-aligned -> float4 LDS read/write.
// b128 bank map: quarter-wave (16 lanes) covers every bank exactly 2x
// on both the coop write and the per-row read -> conflict-free.
#define XPAD 36

// ---------------------------------------------------------------------------
// Fused kernel: min-dist over 24 atoms + 3x GEMV [128 -> 10] + activations.
// One thread per (b, l, p) == one row of Interact. 256 rows per block.
//
// R3 fix: pi/sigma/mu stores were 8B-per-lane at 40B stride -> ~5x sectored
// write amplification at TCC (318 MB vs 67 MB ideal, measured). Outputs now
// staged through LDS (reusing xs) and stored as dense per-wave 512B chunks.
// ---------------------------------------------------------------------------
__global__ __launch_bounds__(256, 4) void k_fused(
    const float* __restrict__ pos_l,   // [B, NL, 3]
    const float* __restrict__ pos_p,   // [B, NP, 24, 3]
    const int*   __restrict__ mask,    // [B, NL, NP] (bool as int32)
    const float* __restrict__ X,       // [ROWS, 128]
    const float* __restrict__ Wpi, const float* __restrict__ bpi,
    const float* __restrict__ Wsg, const float* __restrict__ bsg,
    const float* __restrict__ Wmu, const float* __restrict__ bmu,
    float* __restrict__ out_pi,
    float* __restrict__ out_sg,
    float* __restrict__ out_mu,
    float* __restrict__ dist_out,
    float* __restrict__ mask_out)
{
    __shared__ __align__(16) float xs[256 * XPAD];   // 36 KB -> 4 blocks/CU

    const int tid = threadIdx.x;
    const int idx = blockIdx.x * 256 + tid;     // b*NL*NP + l*NP + p
    const size_t row0 = (size_t)blockIdx.x * 256;

    // Cooperative-load slot mapping (same for every stage):
    // slot s = j*256+tid, r = s>>3, k4 = s&7 -> wave covers 8 rows x 128B.
    int sr[8], sk[8];
    #pragma unroll
    for (int j = 0; j < 8; ++j) {
        int s = j * 256 + tid;
        sr[j] = s >> 3;
        sk[j] = s & 7;
    }

    // ---- issue stage-0 prefetch (latency hides under dist part) ----
    float4 pf[8];
    #pragma unroll
    for (int j = 0; j < 8; ++j)
        pf[j] = *(const float4*)(X + (row0 + sr[j]) * NH + sk[j] * 4);

    // ---------------- distance part ----------------
    float dist_v, mask_v;
    {
        int p  = idx & (NP - 1);
        int bl = idx >> 9;                      // b*NL + l
        int b  = bl >> 6;

        const float* xl = pos_l + bl * 3;
        float x0 = xl[0], x1 = xl[1], x2 = xl[2];
        float qs = x0 * x0 + x1 * x1 + x2 * x2;

        // 24 atoms * 3 floats = 18 float4 per residue (288B rows, 16B aligned)
        const float4* yp = (const float4*)(pos_p + ((size_t)(b * NP + p)) * 72);

        // min over clamped d2; d2<0 -> NaN -> 10000 in the reference:
        // clamp to 1e8 (=10000^2 exactly) and take one sqrt at the end.
        float m2 = 1e30f;
        #pragma unroll
        for (int q = 0; q < 6; ++q) {           // 4 atoms per iteration
            float4 v0 = yp[q * 3 + 0];
            float4 v1 = yp[q * 3 + 1];
            float4 v2 = yp[q * 3 + 2];
            float c[12] = {v0.x, v0.y, v0.z, v0.w,
                           v1.x, v1.y, v1.z, v1.w,
                           v2.x, v2.y, v2.z, v2.w};
            #pragma unroll
            for (int a = 0; a < 4; ++a) {
                float yx = c[a * 3 + 0], yy = c[a * 3 + 1], yz = c[a * 3 + 2];
                float d2 = qs + (yx * yx + yy * yy + yz * yz)
                              - 2.0f * (x0 * yx + x1 * yy + x2 * yz);
                d2 = (d2 >= 0.0f) ? d2 : 1e8f;
                m2 = fminf(m2, d2);
            }
        }
        float m = sqrtf(m2);

        int mk = mask[idx];
        dist_v = mk ? m : 0.0f;
        mask_v = mk ? 1.0f : 0.0f;
    }
    // dense per-wave stores (4B/lane contiguous): no amplification
    dist_out[idx] = dist_v;
    mask_out[idx] = mask_v;

    // ---------------- GEMV part ----------------
    float accp[NG], accs[NG], accm[NG];
    #pragma unroll
    for (int g = 0; g < NG; ++g) {              // uniform-index -> s_load
        accp[g] = bpi[g];
        accs[g] = bsg[g];
        accm[g] = bmu[g];
    }

    for (int kc = 0; kc < 4; ++kc) {
        __syncthreads();                        // prev-stage reads complete
        #pragma unroll
        for (int j = 0; j < 8; ++j)             // regs -> LDS (b128 writes)
            *(float4*)&xs[sr[j] * XPAD + sk[j] * 4] = pf[j];
        __syncthreads();                        // tile visible to all

        if (kc < 3) {                           // issue next-stage loads;
            #pragma unroll                      // they fly during compute
            for (int j = 0; j < 8; ++j)
                pf[j] = *(const float4*)(X + (row0 + sr[j]) * NH
                                           + (kc + 1) * 32 + sk[j] * 4);
        }

        const float4* xr4 = (const float4*)&xs[tid * XPAD];
        #pragma unroll
        for (int k4 = 0; k4 < 8; ++k4) {
            float4 h4 = xr4[k4];                // ds_read_b128, conflict-free
            float hk[4] = {h4.x, h4.y, h4.z, h4.w};
            #pragma unroll
            for (int kk = 0; kk < 4; ++kk) {
                int kg = kc * 32 + k4 * 4 + kk; // wave-uniform
                const float* wp = Wpi + kg * NG;
                const float* ws = Wsg + kg * NG;
                const float* wm = Wmu + kg * NG;
                float h = hk[kk];
                #pragma unroll
                for (int g = 0; g < NG; ++g) {
                    accp[g] = fmaf(h, wp[g], accp[g]);
                    accs[g] = fmaf(h, ws[g], accs[g]);
                    accm[g] = fmaf(h, wm[g], accm[g]);
                }
            }
        }
    }

    // ---------------- activations (in regs) ----------------
    float pi[NG], sg[NG], mu[NG];

    // pi = softmax(accp)
    float mx = accp[0];
    #pragma unroll
    for (int g = 1; g < NG; ++g) mx = fmaxf(mx, accp[g]);
    float ssum = 0.0f;
    #pragma unroll
    for (int g = 0; g < NG; ++g) { pi[g] = __expf(accp[g] - mx); ssum += pi[g]; }
    float inv = 1.0f / ssum;
    #pragma unroll
    for (int g = 0; g < NG; ++g) pi[g] *= inv;

    // sigma = clip(leaky(accs) + 1.1, 1e-6, inf)
    #pragma unroll
    for (int g = 0; g < NG; ++g) {
        float x = accs[g];
        sg[g] = fmaxf((x >= 0.0f ? x : 0.01f * x) + 1.1f, 1e-6f);
    }

    // mu = leaky(accm) + 1.0
    #pragma unroll
    for (int g = 0; g < NG; ++g) {
        float x = accm[g];
        mu[g] = (x >= 0.0f ? x : 0.01f * x) + 1.0f;
    }

    // ---------------- dense output via LDS transpose ----------------
    // Reuse xs: 3 arrays x [256][10] floats = 30720 B <= 36864 B.
    __syncthreads();                           // all xs reads of stage 3 done
    float* Lp = xs;
    float* Ls = xs + 2560;
    float* Lm = xs + 5120;
    #pragma unroll
    for (int g2 = 0; g2 < 5; ++g2) {           // b64 writes, stride 10/lane:
        *(float2*)&Lp[tid * NG + 2 * g2] = make_float2(pi[2 * g2], pi[2 * g2 + 1]);
        *(float2*)&Ls[tid * NG + 2 * g2] = make_float2(sg[2 * g2], sg[2 * g2 + 1]);
        *(float2*)&Lm[tid * NG + 2 * g2] = make_float2(mu[2 * g2], mu[2 * g2 + 1]);
    }
    __syncthreads();

    // Cooperative dense stores: per inst, wave covers 512 contiguous bytes.
    const size_t fb = row0 * NG;               // block's float offset in region
    #pragma unroll
    for (int j = 0; j < 5; ++j) {
        int s = j * 256 + tid;                 // float2 slot in [0, 1280)
        float2 vp = *(const float2*)&Lp[2 * s];
        float2 vs = *(const float2*)&Ls[2 * s];
        float2 vm = *(const float2*)&Lm[2 * s];
        *(float2*)&out_pi[fb + 2 * s] = vp;
        *(float2*)&out_sg[fb + 2 * s] = vs;
        *(float2*)&out_mu[fb + 2 * s] = vm;
    }
}

// ---------------------------------------------------------------------------
extern "C" void kernel_launch(void* const* d_in, const int* in_sizes, int n_in,
                              void* d_out, int out_size, void* d_ws, size_t ws_size,
                              hipStream_t stream) {
    const float* pos_l    = (const float*)d_in[0];
    const float* pos_p    = (const float*)d_in[1];
    const float* Interact = (const float*)d_in[2];
    const int*   mask     = (const int*)  d_in[3];
    const float* Wpi      = (const float*)d_in[4];
    const float* bpi      = (const float*)d_in[5];
    const float* Wsg      = (const float*)d_in[6];
    const float* bsg      = (const float*)d_in[7];
    const float* Wmu      = (const float*)d_in[8];
    const float* bmu      = (const float*)d_in[9];

    float* out      = (float*)d_out;
    float* out_pi   = out + OFF_PI;
    float* out_sg   = out + OFF_SIGMA;
    float* out_mu   = out + OFF_MU;
    float* out_dist = out + OFF_DIST;
    float* out_mask = out + OFF_MASK;

    hipLaunchKernelGGL(k_fused, dim3(ROWS / 256), dim3(256), 0, stream,
                       pos_l, pos_p, mask, Interact,
                       Wpi, bpi, Wsg, bsg, Wmu, bmu,
                       out_pi, out_sg, out_mu, out_dist, out_mask);
}